// Round 21
// baseline (118.033 us; speedup 1.0000x reference)
//
#include <hip/hip_runtime.h>
#include <hip/hip_bf16.h>
#include <math.h>

#define NN   1024
#define GG   16
#define DGD  64
#define CLS  80
#define SPLIT 4
#define JT_PER 4   // 16 j-tiles / SPLIT

typedef __attribute__((ext_vector_type(8))) short short8;
typedef __attribute__((ext_vector_type(4))) float f32x4;
typedef _Float16 half8 __attribute__((ext_vector_type(8)));

// Cheap truncation split: x ~= h + l (bf16 planes).
__device__ inline void split2t(float x, ushort& h, ushort& l) {
  uint u = __float_as_uint(x);
  h = (ushort)(u >> 16);
  float r = x - __uint_as_float(u & 0xFFFF0000u);
  l = (ushort)(__float_as_uint(r) >> 16);
}

__device__ inline ushort f32tof16(float x) {
  _Float16 h = (_Float16)x;
  return *(ushort*)&h;
}
__device__ inline float f16tof32(ushort u) {
  _Float16 h; *(ushort*)&h = u;
  return (float)h;
}

// Swizzled LDS slots (16B short8 units): write row r, K-chunk kc; read frag f.
__device__ inline int wslot(int r, int kc) {
  return ((r >> 4) << 6) + ((kc & 3) << 4) + ((r & 15) ^ ((kc & 3) << 2));
}
__device__ inline int rslot(int f, int lane) {
  return (f << 6) + ((lane >> 4) << 4) + ((lane & 15) ^ ((lane >> 4) << 2));
}

// ---------------------------------------------------------------------------
// Prep (one launch): bid<256 roi split | [256,512) Wc split | [512,1024) WT.
// ---------------------------------------------------------------------------
__global__ __launch_bounds__(256) void prep_k(
    const float* __restrict__ roi, ushort* __restrict__ roiH, ushort* __restrict__ roiL,
    const float* __restrict__ Wc,  ushort* __restrict__ WcH,  ushort* __restrict__ WcL,
    const float* __restrict__ Wq,  const float* __restrict__ Wk,
    ushort* __restrict__ WqTH, ushort* __restrict__ WqTL,
    ushort* __restrict__ WkTH, ushort* __restrict__ WkTL)
{
  __shared__ float Tl[64][68];
  const int bid = blockIdx.x;
  const int t = threadIdx.x;

  if (bid < 512) {
    const float* src = bid < 256 ? roi : Wc;
    ushort* H = bid < 256 ? roiH : WcH;
    ushort* L = bid < 256 ? roiL : WcL;
    const int base = ((bid & 255) * 256 + t) * 16;
    float v[16];
    *(float4*)&v[0]  = *(const float4*)&src[base];
    *(float4*)&v[4]  = *(const float4*)&src[base + 4];
    *(float4*)&v[8]  = *(const float4*)&src[base + 8];
    *(float4*)&v[12] = *(const float4*)&src[base + 12];
    ushort hs[16], ls[16];
#pragma unroll
    for (int u = 0; u < 16; ++u) split2t(v[u], hs[u], ls[u]);
    *(uint4*)&H[base]     = *(uint4*)&hs[0];
    *(uint4*)&H[base + 8] = *(uint4*)&hs[8];
    *(uint4*)&L[base]     = *(uint4*)&ls[0];
    *(uint4*)&L[base + 8] = *(uint4*)&ls[8];
  } else {
    const int s = bid - 512;
    const float* W = (s >> 8) ? Wk : Wq;
    ushort* H = (s >> 8) ? WkTH : WqTH;
    ushort* L = (s >> 8) ? WkTL : WqTL;
    const int rb = s & 255;
    const int j0 = (rb & 15) * 64, k0 = (rb >> 4) * 64;
    const int r = t >> 2, c = (t & 3) * 16;
#pragma unroll
    for (int u = 0; u < 4; ++u)
      *(float4*)&Tl[r][c + u * 4] = *(const float4*)&W[(k0 + r) * NN + j0 + c + u * 4];
    __syncthreads();
    ushort hs[16], ls[16];
#pragma unroll
    for (int u = 0; u < 16; ++u) split2t(Tl[c + u][r], hs[u], ls[u]);
    const int ob = (j0 + r) * NN + k0 + c;
    *(uint4*)&H[ob]     = *(uint4*)&hs[0];
    *(uint4*)&H[ob + 8] = *(uint4*)&hs[8];
    *(uint4*)&L[ob]     = *(uint4*)&ls[0];
    *(uint4*)&L[ob + 8] = *(uint4*)&ls[8];
  }
}

// ---------------------------------------------------------------------------
// FUSED kernel: 2816 blocks = 128*22; bid%22<6 -> gemm (768: 512 qk + 256
// rwt, 64x64 tiles, full K, 1-deep prefetch), else posaff HALF-row (2048).
// Half-rows double the posaff block count -> 11 blocks/CU launched, 8
// resident (wave-slot cap) vs 7 before: more co-resident VALU waves.
// ---------------------------------------------------------------------------
__global__ __launch_bounds__(256) void fused_m(
    const float* __restrict__ bbox, const float* __restrict__ Wp,
    const float* __restrict__ bp,
    const ushort* __restrict__ roiH, const ushort* __restrict__ roiL,
    const ushort* __restrict__ WqTH, const ushort* __restrict__ WqTL,
    const ushort* __restrict__ WkTH, const ushort* __restrict__ WkTL,
    const ushort* __restrict__ WcH,  const ushort* __restrict__ WcL,
    const float* __restrict__ bq, const float* __restrict__ bk,
    ushort* __restrict__ qHp, ushort* __restrict__ qLp,
    ushort* __restrict__ kHp, ushort* __restrict__ kLp,
    ushort* __restrict__ rwHp, ushort* __restrict__ rwLp,
    ushort* __restrict__ paffh)
{
  __shared__ short8 sAH[256], sAL[256], sBH[256], sBL[256];   // 16KB
  const int bid = blockIdx.x;
  const int t = threadIdx.x, lane = t & 63, w = t >> 6;

  if (bid % 22 < 6) {
    // ---- gemm role: C[64x64] = A[64xK] x B[64xK]^T, full K=1024 ----
    const int gi = (bid / 22) * 6 + (bid % 22);   // 0..767
    const int crow = (lane >> 4) * 4, ccol = lane & 15;
    const int kc = t & 3, r = t >> 2;
    const int sl0 = wslot(r, kc);
    const int wr = w >> 1, wc = w & 1;

    const ushort *AH_, *AL_, *BH_, *BL_;
    const float* bias;
    ushort *OH_, *OL_;
    int j0;
    if (gi < 512) {
      const int z = gi >> 8, rb = gi & 255;
      const int i0 = (rb >> 4) * 64;
      j0 = (rb & 15) * 64;
      AH_ = roiH + (size_t)i0 * NN;
      AL_ = roiL + (size_t)i0 * NN;
      BH_ = z ? WkTH : WqTH;
      BL_ = z ? WkTL : WqTL;
      bias = z ? bk : bq;
      OH_ = (z ? kHp : qHp) + (size_t)i0 * NN;
      OL_ = (z ? kLp : qLp) + (size_t)i0 * NN;
    } else {
      const int s = gi - 512;
      const int g = s >> 4;
      j0 = (s & 15) * 64;
      AH_ = WcH + (size_t)g * DGD * NN;
      AL_ = WcL + (size_t)g * DGD * NN;
      BH_ = roiH;
      BL_ = roiL;
      bias = nullptr;
      OH_ = rwHp + (size_t)g * DGD * NN;
      OL_ = rwLp + (size_t)g * DGD * NN;
    }

    uint4 vah, val, vbh, vbl;
#define LOADT(kt) { const int ka = (kt) * 32 + (kc << 3); \
    vah = *(const uint4*)&AH_[(size_t)r * NN + ka]; \
    val = *(const uint4*)&AL_[(size_t)r * NN + ka]; \
    vbh = *(const uint4*)&BH_[(size_t)(j0 + r) * NN + ka]; \
    vbl = *(const uint4*)&BL_[(size_t)(j0 + r) * NN + ka]; }

    LOADT(0);
    f32x4 acc[2][2] = {};
    for (int kt = 0; kt < 32; ++kt) {
      __syncthreads();
      *(uint4*)&sAH[sl0] = vah; *(uint4*)&sAL[sl0] = val;
      *(uint4*)&sBH[sl0] = vbh; *(uint4*)&sBL[sl0] = vbl;
      __syncthreads();
      if (kt + 1 < 32) LOADT(kt + 1);
      short8 ah[2], al[2], bh[2], bl[2];
#pragma unroll
      for (int f = 0; f < 2; ++f) {
        ah[f] = sAH[rslot(wr * 2 + f, lane)];
        al[f] = sAL[rslot(wr * 2 + f, lane)];
        bh[f] = sBH[rslot(wc * 2 + f, lane)];
        bl[f] = sBL[rslot(wc * 2 + f, lane)];
      }
#pragma unroll
      for (int fm = 0; fm < 2; ++fm)
#pragma unroll
        for (int fn = 0; fn < 2; ++fn) {
          acc[fm][fn] = __builtin_amdgcn_mfma_f32_16x16x32_bf16(ah[fm], bh[fn], acc[fm][fn], 0, 0, 0);
          acc[fm][fn] = __builtin_amdgcn_mfma_f32_16x16x32_bf16(ah[fm], bl[fn], acc[fm][fn], 0, 0, 0);
          acc[fm][fn] = __builtin_amdgcn_mfma_f32_16x16x32_bf16(al[fm], bh[fn], acc[fm][fn], 0, 0, 0);
        }
    }
#undef LOADT
#pragma unroll
    for (int fm = 0; fm < 2; ++fm) {
      const int row = wr * 32 + fm * 16 + crow;
#pragma unroll
      for (int fn = 0; fn < 2; ++fn) {
        const int col = j0 + wc * 32 + fn * 16 + ccol;
        const float bb = bias ? bias[col] : 0.0f;
#pragma unroll
        for (int e = 0; e < 4; ++e) {
          ushort hh, ll; split2t(acc[fm][fn][e] + bb, hh, ll);
          OH_[(size_t)(row + e) * NN + col] = hh;
          OL_[(size_t)(row + e) * NN + col] = ll;
        }
      }
    }
  } else {
    // ---- posaff role (f16 + small-angle polys): HALF-row of paff (f16) ----
    const int idx  = (bid / 22) * 16 + (bid % 22) - 6;   // 0..2047
    const int i    = idx >> 1;
    const int half = idx & 1;
    half8* sWH = (half8*)sAH;          // alias gemm LDS (2KB each)
    half8* sWL = (half8*)sAL;
    float* bpS = (float*)sBH;

    if (t < 128) {
      const int h = t >> 6, kc2 = (t >> 4) & 3, g = t & 15;
      _Float16 hh[8], ll[8];
#pragma unroll
      for (int u = 0; u < 8; ++u) {
        float x = Wp[(h * 32 + kc2 * 8 + u) * 16 + g];
        _Float16 xh = (_Float16)x;
        hh[u] = xh;
        ll[u] = (_Float16)(x - (float)xh);
      }
      sWH[t] = *(half8*)&hh[0];
      sWL[t] = *(half8*)&ll[0];
    }
    if (t < 16) bpS[t] = bp[t];
    __syncthreads();

    const half8 wh0 = sWH[lane], wh1 = sWH[64 + lane];
    const half8 wl0 = sWL[lane], wl1 = sWL[64 + lane];
    const float bb = bpS[lane & 15];

    const float xi0 = bbox[i*4+0], yi0 = bbox[i*4+1], xi1 = bbox[i*4+2], yi1 = bbox[i*4+3];
    const float wi = xi1 - xi0 + 1.0f, hi = yi1 - yi0 + 1.0f;
    const float cxi = 0.5f*(xi0+xi1), cyi = 0.5f*(yi0+yi1);

    const int jr = lane & 15, p = lane >> 4;
    const int csel = p >> 1;
    const bool iscos = (p & 1);
    const float shift = iscos ? 1.5707963267948966f : 0.0f;

    const float invdim[8] = {1.0f, 0.42169650342858224f, 0.17782794100389228f,
        0.07498942093324558f, 0.03162277660168379f, 0.01333521432163324f,
        0.005623413251903491f, 0.0023713737056616554f};

#pragma unroll 1
    for (int f = 0; f < 8; ++f) {
      const int j0 = half * 512 + w * 128 + f * 16;
      float4 bj = *(const float4*)&bbox[(j0 + jr) * 4];
      const float wj = bj.z - bj.x + 1.0f, hj = bj.w - bj.y + 1.0f;
      const float cxj = 0.5f*(bj.x+bj.z), cyj = 0.5f*(bj.y+bj.w);

      const float num1 = csel ? (cyi - cyj) : (cxi - cxj);
      const float den1 = csel ? hi : wi;
      const float pos1 = __logf(fmaxf(fabsf(num1 / den1), 1e-3f));
      const float num2 = csel ? hi : wi;
      const float den2 = csel ? hj : wj;
      const float pos2 = __logf(fmaxf(fabsf(num2 / den2), 1e-3f));

      _Float16 a1[8], a2[8];
#pragma unroll
      for (int u = 0; u < 4; ++u) {
        a1[u] = (_Float16)__sinf(fmaf(pos1, invdim[u], shift));
        a2[u] = (_Float16)__sinf(fmaf(pos2, invdim[u], shift));
      }
#pragma unroll
      for (int u = 4; u < 8; ++u) {
        const float b1 = pos1 * invdim[u];
        const float b2 = pos2 * invdim[u];
        const float q1 = b1 * b1, q2 = b2 * b2;
        const float s1 = b1 * fmaf(q1, -0.16666667f, 1.0f);
        const float c1 = fmaf(q1, -0.5f, 1.0f);
        const float s2 = b2 * fmaf(q2, -0.16666667f, 1.0f);
        const float c2 = fmaf(q2, -0.5f, 1.0f);
        a1[u] = (_Float16)(iscos ? c1 : s1);
        a2[u] = (_Float16)(iscos ? c2 : s2);
      }
      const half8 A1 = *(half8*)&a1[0];
      const half8 A2 = *(half8*)&a2[0];

      f32x4 acc = {0.f, 0.f, 0.f, 0.f};
      acc = __builtin_amdgcn_mfma_f32_16x16x32_f16(A1, wh0, acc, 0, 0, 0);
      acc = __builtin_amdgcn_mfma_f32_16x16x32_f16(A2, wh1, acc, 0, 0, 0);
      acc = __builtin_amdgcn_mfma_f32_16x16x32_f16(A1, wl0, acc, 0, 0, 0);
      acc = __builtin_amdgcn_mfma_f32_16x16x32_f16(A2, wl1, acc, 0, 0, 0);

      ushort o4[4];
      o4[0] = f32tof16(__logf(fmaxf(acc[0] + bb, 1e-6f)));
      o4[1] = f32tof16(__logf(fmaxf(acc[1] + bb, 1e-6f)));
      o4[2] = f32tof16(__logf(fmaxf(acc[2] + bb, 1e-6f)));
      o4[3] = f32tof16(__logf(fmaxf(acc[3] + bb, 1e-6f)));
      *(short4*)&paffh[((i * GG + (lane & 15)) << 10) + j0 + p * 4] = *(short4*)&o4[0];
    }
  }
}

// ---------------------------------------------------------------------------
// Kernel 4 (MFMA flash): block = 64 i-rows x g, SPLIT=4 over j (R16 proven).
// Register-staged, swizzled LDS; paff read as f16.
// ---------------------------------------------------------------------------
__global__ __launch_bounds__(256) void attn_m(
    const ushort* __restrict__ qhp, const ushort* __restrict__ qlp,
    const ushort* __restrict__ khp, const ushort* __restrict__ klp,
    const ushort* __restrict__ rwhp, const ushort* __restrict__ rwlp,
    const ushort* __restrict__ paffh,
    float* __restrict__ po, float* __restrict__ pstat)
{
  const int g  = blockIdx.y;
  const int i0 = blockIdx.x * 64;
  const int sp = blockIdx.z;
  const int t  = threadIdx.x;
  const int lane = t & 63, w = t >> 6;

  __shared__ short8 sKH[512], sKL[512], sRH[512], sRL[512];
  __shared__ float PT[4][16][68];

  const int r  = t >> 2;
  const int kc = t & 3;
  const int sl = wslot(r, kc);

  // ---- stage Q via K buffers, extract frags to registers ----
  {
    const ushort* s0 = qhp + (size_t)(i0 + r) * NN + g * DGD + kc * 8;
    const ushort* s1 = qlp + (size_t)(i0 + r) * NN + g * DGD + kc * 8;
    *(uint4*)&sKH[sl]       = *(const uint4*)&s0[0];
    *(uint4*)&sKH[sl + 256] = *(const uint4*)&s0[32];
    *(uint4*)&sKL[sl]       = *(const uint4*)&s1[0];
    *(uint4*)&sKL[sl + 256] = *(const uint4*)&s1[32];
  }
  __syncthreads();
  const int qsl = rslot(w, lane);
  const short8 qf_h0 = sKH[qsl], qf_h1 = sKH[256 + qsl];
  const short8 qf_l0 = sKL[qsl], qf_l1 = sKL[256 + qsl];

  const int qr = (lane >> 4) * 4;
  const int qc = lane & 15;

  float m[4], l[4];
  f32x4 o[4] = {};
#pragma unroll
  for (int e = 0; e < 4; ++e) { m[e] = -1e30f; l[e] = 0.f; }

#pragma unroll 1
  for (int jt = sp * JT_PER; jt < sp * JT_PER + JT_PER; ++jt) {
    const int j0 = jt * 64;
    const ushort* ks0 = khp + (size_t)(j0 + r) * NN + g * DGD + kc * 8;
    const ushort* ks1 = klp + (size_t)(j0 + r) * NN + g * DGD + kc * 8;
    uint4 kv00 = *(const uint4*)&ks0[0], kv01 = *(const uint4*)&ks0[32];
    uint4 kv10 = *(const uint4*)&ks1[0], kv11 = *(const uint4*)&ks1[32];
    const ushort* rs0 = rwhp + ((size_t)g * DGD + r) * NN + j0 + kc * 8;
    const ushort* rs1 = rwlp + ((size_t)g * DGD + r) * NN + j0 + kc * 8;
    uint4 rv00 = *(const uint4*)&rs0[0], rv01 = *(const uint4*)&rs0[32];
    uint4 rv10 = *(const uint4*)&rs1[0], rv11 = *(const uint4*)&rs1[32];
    float pf[4][4];
#pragma unroll
    for (int jf = 0; jf < 4; ++jf)
#pragma unroll
      for (int e = 0; e < 4; ++e)
        pf[jf][e] = f16tof32(paffh[(((i0 + w * 16 + qr + e) * GG + g) << 10) + j0 + jf * 16 + qc]);

    __syncthreads();   // A: prev MFMA reads (and Q extraction) done
    *(uint4*)&sKH[sl] = kv00; *(uint4*)&sKH[sl + 256] = kv01;
    *(uint4*)&sKL[sl] = kv10; *(uint4*)&sKL[sl + 256] = kv11;
    *(uint4*)&sRH[sl] = rv00; *(uint4*)&sRH[sl + 256] = rv01;
    *(uint4*)&sRL[sl] = rv10; *(uint4*)&sRL[sl + 256] = rv11;
    __syncthreads();   // B: tiles visible

    // ---- QK^T (split-3) ----
    f32x4 s4[4];
#pragma unroll
    for (int jf = 0; jf < 4; ++jf) {
      const int bs = rslot(jf, lane);
      short8 bh0 = sKH[bs], bh1 = sKH[256 + bs];
      short8 bl0 = sKL[bs], bl1 = sKL[256 + bs];
      f32x4 a = {0.f, 0.f, 0.f, 0.f};
      a = __builtin_amdgcn_mfma_f32_16x16x32_bf16(qf_h0, bh0, a, 0, 0, 0);
      a = __builtin_amdgcn_mfma_f32_16x16x32_bf16(qf_h1, bh1, a, 0, 0, 0);
      a = __builtin_amdgcn_mfma_f32_16x16x32_bf16(qf_h0, bl0, a, 0, 0, 0);
      a = __builtin_amdgcn_mfma_f32_16x16x32_bf16(qf_h1, bl1, a, 0, 0, 0);
      a = __builtin_amdgcn_mfma_f32_16x16x32_bf16(qf_l0, bh0, a, 0, 0, 0);
      a = __builtin_amdgcn_mfma_f32_16x16x32_bf16(qf_l1, bh1, a, 0, 0, 0);
      s4[jf] = a;
    }

    // ---- online softmax ----
#pragma unroll
    for (int e = 0; e < 4; ++e) {
      float v0 = fmaf(s4[0][e], 0.125f, pf[0][e]);
      float v1 = fmaf(s4[1][e], 0.125f, pf[1][e]);
      float v2 = fmaf(s4[2][e], 0.125f, pf[2][e]);
      float v3 = fmaf(s4[3][e], 0.125f, pf[3][e]);
      float tm = fmaxf(fmaxf(v0, v1), fmaxf(v2, v3));
#pragma unroll
      for (int off = 1; off < 16; off <<= 1) tm = fmaxf(tm, __shfl_xor(tm, off, 64));
      const float mn = fmaxf(m[e], tm);
      const float sc = __expf(m[e] - mn);
      v0 = __expf(v0 - mn); v1 = __expf(v1 - mn);
      v2 = __expf(v2 - mn); v3 = __expf(v3 - mn);
      float ts = (v0 + v1) + (v2 + v3);
#pragma unroll
      for (int off = 1; off < 16; off <<= 1) ts += __shfl_xor(ts, off, 64);
      l[e] = l[e] * sc + ts;
      m[e] = mn;
#pragma unroll
      for (int nf = 0; nf < 4; ++nf) o[nf][e] *= sc;
      PT[w][qr + e][ 0 + qc] = v0;
      PT[w][qr + e][16 + qc] = v1;
      PT[w][qr + e][32 + qc] = v2;
      PT[w][qr + e][48 + qc] = v3;
    }

    // ---- P frags + split ----
    short8 ph[2], pl[2];
#pragma unroll
    for (int h = 0; h < 2; ++h) {
      const float* psrc = &PT[w][lane & 15][h * 32 + (lane >> 4) * 8];
      float4 x = *(const float4*)&psrc[0];
      float4 y = *(const float4*)&psrc[4];
      float vv[8] = {x.x, x.y, x.z, x.w, y.x, y.y, y.z, y.w};
      ushort hh[8], ll[8];
#pragma unroll
      for (int u = 0; u < 8; ++u) split2t(vv[u], hh[u], ll[u]);
      ph[h] = *(short8*)&hh[0];
      pl[h] = *(short8*)&ll[0];
    }

    // ---- PV (split-3) ----
#pragma unroll
    for (int nf = 0; nf < 4; ++nf) {
      const int bs = rslot(nf, lane);
      short8 rh0 = sRH[bs], rh1 = sRH[256 + bs];
      short8 rl0 = sRL[bs], rl1 = sRL[256 + bs];
      f32x4 a = o[nf];
      a = __builtin_amdgcn_mfma_f32_16x16x32_bf16(ph[0], rh0, a, 0, 0, 0);
      a = __builtin_amdgcn_mfma_f32_16x16x32_bf16(ph[1], rh1, a, 0, 0, 0);
      a = __builtin_amdgcn_mfma_f32_16x16x32_bf16(ph[0], rl0, a, 0, 0, 0);
      a = __builtin_amdgcn_mfma_f32_16x16x32_bf16(ph[1], rl1, a, 0, 0, 0);
      a = __builtin_amdgcn_mfma_f32_16x16x32_bf16(pl[0], rh0, a, 0, 0, 0);
      a = __builtin_amdgcn_mfma_f32_16x16x32_bf16(pl[1], rh1, a, 0, 0, 0);
      o[nf] = a;
    }
  }

  const size_t idx = ((size_t)blockIdx.x * GG + g) * SPLIT + sp;
  float* pot = po + idx * 4096;
#pragma unroll
  for (int nf = 0; nf < 4; ++nf)
#pragma unroll
    for (int e = 0; e < 4; ++e)
      pot[(w * 16 + qr + e) * 64 + nf * 16 + qc] = o[nf][e];
  if (qc == 0) {
#pragma unroll
    for (int e = 0; e < 4; ++e) {
      const int row = w * 16 + qr + e;
      pstat[(idx * 64 + row) * 2]     = m[e];
      pstat[(idx * 64 + row) * 2 + 1] = l[e];
    }
  }
}

// ---------------------------------------------------------------------------
// Kernel 4b: combine split partials (+ residual + bias) -> per-block column
// partial sums only (res materialization removed — nothing reads it).
// ---------------------------------------------------------------------------
__global__ __launch_bounds__(256) void combine_k(
    const float* __restrict__ po, const float* __restrict__ pstat,
    const float* __restrict__ roi, const float* __restrict__ bconv,
    float* __restrict__ part2)
{
  __shared__ float T[64][68];
  const int it = blockIdx.x, g = blockIdx.y;
  const int t = threadIdx.x;
  const int row = t >> 2, c0 = (t & 3) * 16;
  const size_t base = ((size_t)it * GG + g) * SPLIT;

  float ms[SPLIT], ls[SPLIT];
#pragma unroll
  for (int s = 0; s < SPLIT; ++s) {
    float2 st = *(const float2*)&pstat[((base + s) * 64 + row) * 2];
    ms[s] = st.x; ls[s] = st.y;
  }
  float M = ms[0];
#pragma unroll
  for (int s = 1; s < SPLIT; ++s) M = fmaxf(M, ms[s]);
  float wgt[SPLIT], L = 0.f;
#pragma unroll
  for (int s = 0; s < SPLIT; ++s) { wgt[s] = __expf(ms[s] - M); L = fmaf(ls[s], wgt[s], L); }
  const float rL = 1.0f / L;

  const int grow = it * 64 + row;
  const int f0   = g * DGD + c0;
#pragma unroll
  for (int c = 0; c < 4; ++c) {
    float4 acc = {0.f, 0.f, 0.f, 0.f};
#pragma unroll
    for (int s = 0; s < SPLIT; ++s) {
      float4 v = *(const float4*)&po[(base + s) * 4096 + row * 64 + c0 + c * 4];
      acc.x = fmaf(v.x, wgt[s], acc.x);
      acc.y = fmaf(v.y, wgt[s], acc.y);
      acc.z = fmaf(v.z, wgt[s], acc.z);
      acc.w = fmaf(v.w, wgt[s], acc.w);
    }
    float4 r4 = *(const float4*)&roi[grow * NN + f0 + c * 4];
    float4 b4 = *(const float4*)&bconv[f0 + c * 4];
    float4 ov;
    ov.x = r4.x + b4.x + acc.x * rL;
    ov.y = r4.y + b4.y + acc.y * rL;
    ov.z = r4.z + b4.z + acc.z * rL;
    ov.w = r4.w + b4.w + acc.w * rL;
    *(float4*)&T[row][c0 + c * 4] = ov;
  }
  __syncthreads();
  if (t < 64) {
    float s = 0.f;
#pragma unroll 8
    for (int rr = 0; rr < 64; ++rr) s += T[rr][t];
    part2[(size_t)it * NN + g * DGD + t] = s;
  }
}

// ---------------------------------------------------------------------------
// Kernel 5: reduce 16 partials, logits = colsum@W_ro + b_ro, sigmoid.
// ---------------------------------------------------------------------------
__global__ __launch_bounds__(640) void final_k(
    const float* __restrict__ part2, const float* __restrict__ W_ro,
    const float* __restrict__ b_ro, float* __restrict__ out)
{
  __shared__ float cs[1024];
  __shared__ float red[8][CLS];
  const int t = threadIdx.x;

  for (int u = t; u < 1024; u += 640) {
    float s = 0.f;
#pragma unroll
    for (int p = 0; p < 16; ++p) s += part2[(size_t)p * NN + u];
    cs[u] = s;
  }
  __syncthreads();

  {
    const int c = t % CLS, s = t / CLS;
    float acc = 0.f;
    const int d0 = s * 128;
#pragma unroll 8
    for (int d = d0; d < d0 + 128; ++d)
      acc = fmaf(cs[d], W_ro[d * CLS + c], acc);
    red[s][c] = acc;
  }
  __syncthreads();

  if (t < CLS) {
    float lg = b_ro[t];
#pragma unroll
    for (int s = 0; s < 8; ++s) lg += red[s][t];
    out[t] = 1.0f / (1.0f + __expf(-lg));
  }
}

// ---------------------------------------------------------------------------
extern "C" void kernel_launch(void* const* d_in, const int* in_sizes, int n_in,
                              void* d_out, int out_size, void* d_ws, size_t ws_size,
                              hipStream_t stream) {
  const float* bbox  = (const float*)d_in[0];
  const float* roi   = (const float*)d_in[1];
  const float* W_pos = (const float*)d_in[2];
  const float* b_pos = (const float*)d_in[3];
  const float* Wq    = (const float*)d_in[4];
  const float* bq    = (const float*)d_in[5];
  const float* Wk    = (const float*)d_in[6];
  const float* bk    = (const float*)d_in[7];
  const float* Wc    = (const float*)d_in[8];
  const float* bcv   = (const float*)d_in[9];
  const float* W_ro  = (const float*)d_in[10];
  const float* b_ro  = (const float*)d_in[11];

  float* ws = (float*)d_ws;
  // A [0,8M) floats: paff as f16 (16M ushorts = 32 MB)
  ushort* paffh = (ushort*)ws;
  // A2 [8M,12M): po (SPLIT=4 -> 4M floats = 16 MB)
  float* po = ws + (8 << 20);
  // B [16M,20M): prep planes (prep_k -> fused_m); dead after fused_m
  ushort* roiH = (ushort*)(ws + (16 << 20));
  ushort* roiL = (ushort*)(ws + (16 << 20) + (1 << 19));
  ushort* WqTH = (ushort*)(ws + (17 << 20));
  ushort* WqTL = (ushort*)(ws + (17 << 20) + (1 << 19));
  ushort* WkTH = (ushort*)(ws + (18 << 20));
  ushort* WkTL = (ushort*)(ws + (18 << 20) + (1 << 19));
  ushort* WcH  = (ushort*)(ws + (19 << 20));
  ushort* WcL  = (ushort*)(ws + (19 << 20) + (1 << 19));
  // D [20M,23M): q/k/rw split planes (fused_m -> attn)
  ushort* qHp  = (ushort*)(ws + (20 << 20));
  ushort* qLp  = (ushort*)(ws + (20 << 20) + (1 << 19));
  ushort* kHp  = (ushort*)(ws + (21 << 20));
  ushort* kLp  = (ushort*)(ws + (21 << 20) + (1 << 19));
  ushort* rwHp = (ushort*)(ws + (22 << 20));
  ushort* rwLp = (ushort*)(ws + (22 << 20) + (1 << 19));
  // E [23M,24M): pstat (128K floats), part2 (16K). Total 96 MB.
  float* pstat = ws + (23 << 20);                    // 128K floats
  float* part2 = ws + (23 << 20) + (1 << 18);        // 16K floats

  prep_k<<<1024, 256, 0, stream>>>(roi, roiH, roiL, Wc, WcH, WcL,
                                   Wq, Wk, WqTH, WqTL, WkTH, WkTL);

  fused_m<<<2816, 256, 0, stream>>>(bbox, W_pos, b_pos,
                                    roiH, roiL, WqTH, WqTL, WkTH, WkTL,
                                    WcH, WcL, bq, bk,
                                    qHp, qLp, kHp, kLp, rwHp, rwLp, paffh);

  attn_m<<<dim3(16, 16, SPLIT), 256, 0, stream>>>(qHp, qLp, kHp, kLp, rwHp, rwLp,
                                                  paffh, po, pstat);
  combine_k<<<dim3(16, 16), 256, 0, stream>>>(po, pstat, roi, bcv, part2);
  final_k<<<1, 640, 0, stream>>>(part2, W_ro, b_ro, (float*)d_out);
}

// Round 22
// 105.938 us; speedup vs baseline: 1.1142x; 1.1142x over previous
//
#include <hip/hip_runtime.h>
#include <hip/hip_bf16.h>
#include <math.h>

#define NN   1024
#define GG   16
#define DGD  64
#define CLS  80
#define SPLIT 4
#define JT_PER 4   // 16 j-tiles / SPLIT

typedef __attribute__((ext_vector_type(8))) short short8;
typedef __attribute__((ext_vector_type(4))) float f32x4;
typedef _Float16 half8 __attribute__((ext_vector_type(8)));

// Cheap truncation split: x ~= h + l (bf16 planes).
__device__ inline void split2t(float x, ushort& h, ushort& l) {
  uint u = __float_as_uint(x);
  h = (ushort)(u >> 16);
  float r = x - __uint_as_float(u & 0xFFFF0000u);
  l = (ushort)(__float_as_uint(r) >> 16);
}

__device__ inline ushort f32tof16(float x) {
  _Float16 h = (_Float16)x;
  return *(ushort*)&h;
}
__device__ inline float f16tof32(ushort u) {
  _Float16 h; *(ushort*)&h = u;
  return (float)h;
}

// Swizzled LDS slots (16B short8 units): write row r, K-chunk kc; read frag f.
__device__ inline int wslot(int r, int kc) {
  return ((r >> 4) << 6) + ((kc & 3) << 4) + ((r & 15) ^ ((kc & 3) << 2));
}
__device__ inline int rslot(int f, int lane) {
  return (f << 6) + ((lane >> 4) << 4) + ((lane & 15) ^ ((lane >> 4) << 2));
}

// ---------------------------------------------------------------------------
// Prep (one launch): bid<256 roi split | [256,512) Wc split | [512,1024) WT.
// ---------------------------------------------------------------------------
__global__ __launch_bounds__(256) void prep_k(
    const float* __restrict__ roi, ushort* __restrict__ roiH, ushort* __restrict__ roiL,
    const float* __restrict__ Wc,  ushort* __restrict__ WcH,  ushort* __restrict__ WcL,
    const float* __restrict__ Wq,  const float* __restrict__ Wk,
    ushort* __restrict__ WqTH, ushort* __restrict__ WqTL,
    ushort* __restrict__ WkTH, ushort* __restrict__ WkTL)
{
  __shared__ float Tl[64][68];
  const int bid = blockIdx.x;
  const int t = threadIdx.x;

  if (bid < 512) {
    const float* src = bid < 256 ? roi : Wc;
    ushort* H = bid < 256 ? roiH : WcH;
    ushort* L = bid < 256 ? roiL : WcL;
    const int base = ((bid & 255) * 256 + t) * 16;
    float v[16];
    *(float4*)&v[0]  = *(const float4*)&src[base];
    *(float4*)&v[4]  = *(const float4*)&src[base + 4];
    *(float4*)&v[8]  = *(const float4*)&src[base + 8];
    *(float4*)&v[12] = *(const float4*)&src[base + 12];
    ushort hs[16], ls[16];
#pragma unroll
    for (int u = 0; u < 16; ++u) split2t(v[u], hs[u], ls[u]);
    *(uint4*)&H[base]     = *(uint4*)&hs[0];
    *(uint4*)&H[base + 8] = *(uint4*)&hs[8];
    *(uint4*)&L[base]     = *(uint4*)&ls[0];
    *(uint4*)&L[base + 8] = *(uint4*)&ls[8];
  } else {
    const int s = bid - 512;
    const float* W = (s >> 8) ? Wk : Wq;
    ushort* H = (s >> 8) ? WkTH : WqTH;
    ushort* L = (s >> 8) ? WkTL : WqTL;
    const int rb = s & 255;
    const int j0 = (rb & 15) * 64, k0 = (rb >> 4) * 64;
    const int r = t >> 2, c = (t & 3) * 16;
#pragma unroll
    for (int u = 0; u < 4; ++u)
      *(float4*)&Tl[r][c + u * 4] = *(const float4*)&W[(k0 + r) * NN + j0 + c + u * 4];
    __syncthreads();
    ushort hs[16], ls[16];
#pragma unroll
    for (int u = 0; u < 16; ++u) split2t(Tl[c + u][r], hs[u], ls[u]);
    const int ob = (j0 + r) * NN + k0 + c;
    *(uint4*)&H[ob]     = *(uint4*)&hs[0];
    *(uint4*)&H[ob + 8] = *(uint4*)&hs[8];
    *(uint4*)&L[ob]     = *(uint4*)&ls[0];
    *(uint4*)&L[ob + 8] = *(uint4*)&ls[8];
  }
}

// ---------------------------------------------------------------------------
// FUSED kernel: 1792 blocks = 128*14; bid%14<6 -> gemm (768: 512 qk + 256
// rwt, 64x64 tiles, full K, 1-deep prefetch), else posaff FULL row (1024).
// [R20 proven: half-rows (R21) halved prologue amortization and regressed.]
// ---------------------------------------------------------------------------
__global__ __launch_bounds__(256) void fused_m(
    const float* __restrict__ bbox, const float* __restrict__ Wp,
    const float* __restrict__ bp,
    const ushort* __restrict__ roiH, const ushort* __restrict__ roiL,
    const ushort* __restrict__ WqTH, const ushort* __restrict__ WqTL,
    const ushort* __restrict__ WkTH, const ushort* __restrict__ WkTL,
    const ushort* __restrict__ WcH,  const ushort* __restrict__ WcL,
    const float* __restrict__ bq, const float* __restrict__ bk,
    ushort* __restrict__ qHp, ushort* __restrict__ qLp,
    ushort* __restrict__ kHp, ushort* __restrict__ kLp,
    ushort* __restrict__ rwHp, ushort* __restrict__ rwLp,
    ushort* __restrict__ paffh)
{
  __shared__ short8 sAH[256], sAL[256], sBH[256], sBL[256];   // 16KB
  const int bid = blockIdx.x;
  const int t = threadIdx.x, lane = t & 63, w = t >> 6;

  if (bid % 14 < 6) {
    // ---- gemm role: C[64x64] = A[64xK] x B[64xK]^T, full K=1024 ----
    const int gi = (bid / 14) * 6 + (bid % 14);   // 0..767
    const int crow = (lane >> 4) * 4, ccol = lane & 15;
    const int kc = t & 3, r = t >> 2;
    const int sl0 = wslot(r, kc);
    const int wr = w >> 1, wc = w & 1;

    const ushort *AH_, *AL_, *BH_, *BL_;
    const float* bias;
    ushort *OH_, *OL_;
    int j0;
    if (gi < 512) {
      const int z = gi >> 8, rb = gi & 255;
      const int i0 = (rb >> 4) * 64;
      j0 = (rb & 15) * 64;
      AH_ = roiH + (size_t)i0 * NN;
      AL_ = roiL + (size_t)i0 * NN;
      BH_ = z ? WkTH : WqTH;
      BL_ = z ? WkTL : WqTL;
      bias = z ? bk : bq;
      OH_ = (z ? kHp : qHp) + (size_t)i0 * NN;
      OL_ = (z ? kLp : qLp) + (size_t)i0 * NN;
    } else {
      const int s = gi - 512;
      const int g = s >> 4;
      j0 = (s & 15) * 64;
      AH_ = WcH + (size_t)g * DGD * NN;
      AL_ = WcL + (size_t)g * DGD * NN;
      BH_ = roiH;
      BL_ = roiL;
      bias = nullptr;
      OH_ = rwHp + (size_t)g * DGD * NN;
      OL_ = rwLp + (size_t)g * DGD * NN;
    }

    uint4 vah, val, vbh, vbl;
#define LOADT(kt) { const int ka = (kt) * 32 + (kc << 3); \
    vah = *(const uint4*)&AH_[(size_t)r * NN + ka]; \
    val = *(const uint4*)&AL_[(size_t)r * NN + ka]; \
    vbh = *(const uint4*)&BH_[(size_t)(j0 + r) * NN + ka]; \
    vbl = *(const uint4*)&BL_[(size_t)(j0 + r) * NN + ka]; }

    LOADT(0);
    f32x4 acc[2][2] = {};
    for (int kt = 0; kt < 32; ++kt) {
      __syncthreads();
      *(uint4*)&sAH[sl0] = vah; *(uint4*)&sAL[sl0] = val;
      *(uint4*)&sBH[sl0] = vbh; *(uint4*)&sBL[sl0] = vbl;
      __syncthreads();
      if (kt + 1 < 32) LOADT(kt + 1);
      short8 ah[2], al[2], bh[2], bl[2];
#pragma unroll
      for (int f = 0; f < 2; ++f) {
        ah[f] = sAH[rslot(wr * 2 + f, lane)];
        al[f] = sAL[rslot(wr * 2 + f, lane)];
        bh[f] = sBH[rslot(wc * 2 + f, lane)];
        bl[f] = sBL[rslot(wc * 2 + f, lane)];
      }
#pragma unroll
      for (int fm = 0; fm < 2; ++fm)
#pragma unroll
        for (int fn = 0; fn < 2; ++fn) {
          acc[fm][fn] = __builtin_amdgcn_mfma_f32_16x16x32_bf16(ah[fm], bh[fn], acc[fm][fn], 0, 0, 0);
          acc[fm][fn] = __builtin_amdgcn_mfma_f32_16x16x32_bf16(ah[fm], bl[fn], acc[fm][fn], 0, 0, 0);
          acc[fm][fn] = __builtin_amdgcn_mfma_f32_16x16x32_bf16(al[fm], bh[fn], acc[fm][fn], 0, 0, 0);
        }
    }
#undef LOADT
#pragma unroll
    for (int fm = 0; fm < 2; ++fm) {
      const int row = wr * 32 + fm * 16 + crow;
#pragma unroll
      for (int fn = 0; fn < 2; ++fn) {
        const int col = j0 + wc * 32 + fn * 16 + ccol;
        const float bb = bias ? bias[col] : 0.0f;
#pragma unroll
        for (int e = 0; e < 4; ++e) {
          ushort hh, ll; split2t(acc[fm][fn][e] + bb, hh, ll);
          OH_[(size_t)(row + e) * NN + col] = hh;
          OL_[(size_t)(row + e) * NN + col] = ll;
        }
      }
    }
  } else {
    // ---- posaff role (f16 + small-angle polys): one FULL i-row of paff ----
    const int i = (bid / 14) * 8 + (bid % 14) - 6;
    half8* sWH = (half8*)sAH;          // alias gemm LDS (2KB each)
    half8* sWL = (half8*)sAL;
    float* bpS = (float*)sBH;

    if (t < 128) {
      const int h = t >> 6, kc2 = (t >> 4) & 3, g = t & 15;
      _Float16 hh[8], ll[8];
#pragma unroll
      for (int u = 0; u < 8; ++u) {
        float x = Wp[(h * 32 + kc2 * 8 + u) * 16 + g];
        _Float16 xh = (_Float16)x;
        hh[u] = xh;
        ll[u] = (_Float16)(x - (float)xh);
      }
      sWH[t] = *(half8*)&hh[0];
      sWL[t] = *(half8*)&ll[0];
    }
    if (t < 16) bpS[t] = bp[t];
    __syncthreads();

    const half8 wh0 = sWH[lane], wh1 = sWH[64 + lane];
    const half8 wl0 = sWL[lane], wl1 = sWL[64 + lane];
    const float bb = bpS[lane & 15];

    const float xi0 = bbox[i*4+0], yi0 = bbox[i*4+1], xi1 = bbox[i*4+2], yi1 = bbox[i*4+3];
    const float wi = xi1 - xi0 + 1.0f, hi = yi1 - yi0 + 1.0f;
    const float cxi = 0.5f*(xi0+xi1), cyi = 0.5f*(yi0+yi1);

    const int jr = lane & 15, p = lane >> 4;
    const int csel = p >> 1;
    const bool iscos = (p & 1);
    const float shift = iscos ? 1.5707963267948966f : 0.0f;

    const float invdim[8] = {1.0f, 0.42169650342858224f, 0.17782794100389228f,
        0.07498942093324558f, 0.03162277660168379f, 0.01333521432163324f,
        0.005623413251903491f, 0.0023713737056616554f};

#pragma unroll 1
    for (int f = 0; f < 16; ++f) {
      const int j0 = w * 256 + f * 16;
      float4 bj = *(const float4*)&bbox[(j0 + jr) * 4];
      const float wj = bj.z - bj.x + 1.0f, hj = bj.w - bj.y + 1.0f;
      const float cxj = 0.5f*(bj.x+bj.z), cyj = 0.5f*(bj.y+bj.w);

      const float num1 = csel ? (cyi - cyj) : (cxi - cxj);
      const float den1 = csel ? hi : wi;
      const float pos1 = __logf(fmaxf(fabsf(num1 / den1), 1e-3f));
      const float num2 = csel ? hi : wi;
      const float den2 = csel ? hj : wj;
      const float pos2 = __logf(fmaxf(fabsf(num2 / den2), 1e-3f));

      _Float16 a1[8], a2[8];
#pragma unroll
      for (int u = 0; u < 4; ++u) {
        a1[u] = (_Float16)__sinf(fmaf(pos1, invdim[u], shift));
        a2[u] = (_Float16)__sinf(fmaf(pos2, invdim[u], shift));
      }
#pragma unroll
      for (int u = 4; u < 8; ++u) {
        const float b1 = pos1 * invdim[u];
        const float b2 = pos2 * invdim[u];
        const float q1 = b1 * b1, q2 = b2 * b2;
        const float s1 = b1 * fmaf(q1, -0.16666667f, 1.0f);
        const float c1 = fmaf(q1, -0.5f, 1.0f);
        const float s2 = b2 * fmaf(q2, -0.16666667f, 1.0f);
        const float c2 = fmaf(q2, -0.5f, 1.0f);
        a1[u] = (_Float16)(iscos ? c1 : s1);
        a2[u] = (_Float16)(iscos ? c2 : s2);
      }
      const half8 A1 = *(half8*)&a1[0];
      const half8 A2 = *(half8*)&a2[0];

      f32x4 acc = {0.f, 0.f, 0.f, 0.f};
      acc = __builtin_amdgcn_mfma_f32_16x16x32_f16(A1, wh0, acc, 0, 0, 0);
      acc = __builtin_amdgcn_mfma_f32_16x16x32_f16(A2, wh1, acc, 0, 0, 0);
      acc = __builtin_amdgcn_mfma_f32_16x16x32_f16(A1, wl0, acc, 0, 0, 0);
      acc = __builtin_amdgcn_mfma_f32_16x16x32_f16(A2, wl1, acc, 0, 0, 0);

      ushort o4[4];
      o4[0] = f32tof16(__logf(fmaxf(acc[0] + bb, 1e-6f)));
      o4[1] = f32tof16(__logf(fmaxf(acc[1] + bb, 1e-6f)));
      o4[2] = f32tof16(__logf(fmaxf(acc[2] + bb, 1e-6f)));
      o4[3] = f32tof16(__logf(fmaxf(acc[3] + bb, 1e-6f)));
      *(short4*)&paffh[((i * GG + (lane & 15)) << 10) + j0 + p * 4] = *(short4*)&o4[0];
    }
  }
}

// ---------------------------------------------------------------------------
// Kernel 4 (MFMA flash): block = 64 i-rows x g, SPLIT=4 over j (R16 proven).
// Register-staged, swizzled LDS; paff read as f16.
// ---------------------------------------------------------------------------
__global__ __launch_bounds__(256) void attn_m(
    const ushort* __restrict__ qhp, const ushort* __restrict__ qlp,
    const ushort* __restrict__ khp, const ushort* __restrict__ klp,
    const ushort* __restrict__ rwhp, const ushort* __restrict__ rwlp,
    const ushort* __restrict__ paffh,
    float* __restrict__ po, float* __restrict__ pstat)
{
  const int g  = blockIdx.y;
  const int i0 = blockIdx.x * 64;
  const int sp = blockIdx.z;
  const int t  = threadIdx.x;
  const int lane = t & 63, w = t >> 6;

  __shared__ short8 sKH[512], sKL[512], sRH[512], sRL[512];
  __shared__ float PT[4][16][68];

  const int r  = t >> 2;
  const int kc = t & 3;
  const int sl = wslot(r, kc);

  // ---- stage Q via K buffers, extract frags to registers ----
  {
    const ushort* s0 = qhp + (size_t)(i0 + r) * NN + g * DGD + kc * 8;
    const ushort* s1 = qlp + (size_t)(i0 + r) * NN + g * DGD + kc * 8;
    *(uint4*)&sKH[sl]       = *(const uint4*)&s0[0];
    *(uint4*)&sKH[sl + 256] = *(const uint4*)&s0[32];
    *(uint4*)&sKL[sl]       = *(const uint4*)&s1[0];
    *(uint4*)&sKL[sl + 256] = *(const uint4*)&s1[32];
  }
  __syncthreads();
  const int qsl = rslot(w, lane);
  const short8 qf_h0 = sKH[qsl], qf_h1 = sKH[256 + qsl];
  const short8 qf_l0 = sKL[qsl], qf_l1 = sKL[256 + qsl];

  const int qr = (lane >> 4) * 4;
  const int qc = lane & 15;

  float m[4], l[4];
  f32x4 o[4] = {};
#pragma unroll
  for (int e = 0; e < 4; ++e) { m[e] = -1e30f; l[e] = 0.f; }

#pragma unroll 1
  for (int jt = sp * JT_PER; jt < sp * JT_PER + JT_PER; ++jt) {
    const int j0 = jt * 64;
    const ushort* ks0 = khp + (size_t)(j0 + r) * NN + g * DGD + kc * 8;
    const ushort* ks1 = klp + (size_t)(j0 + r) * NN + g * DGD + kc * 8;
    uint4 kv00 = *(const uint4*)&ks0[0], kv01 = *(const uint4*)&ks0[32];
    uint4 kv10 = *(const uint4*)&ks1[0], kv11 = *(const uint4*)&ks1[32];
    const ushort* rs0 = rwhp + ((size_t)g * DGD + r) * NN + j0 + kc * 8;
    const ushort* rs1 = rwlp + ((size_t)g * DGD + r) * NN + j0 + kc * 8;
    uint4 rv00 = *(const uint4*)&rs0[0], rv01 = *(const uint4*)&rs0[32];
    uint4 rv10 = *(const uint4*)&rs1[0], rv11 = *(const uint4*)&rs1[32];
    float pf[4][4];
#pragma unroll
    for (int jf = 0; jf < 4; ++jf)
#pragma unroll
      for (int e = 0; e < 4; ++e)
        pf[jf][e] = f16tof32(paffh[(((i0 + w * 16 + qr + e) * GG + g) << 10) + j0 + jf * 16 + qc]);

    __syncthreads();   // A: prev MFMA reads (and Q extraction) done
    *(uint4*)&sKH[sl] = kv00; *(uint4*)&sKH[sl + 256] = kv01;
    *(uint4*)&sKL[sl] = kv10; *(uint4*)&sKL[sl + 256] = kv11;
    *(uint4*)&sRH[sl] = rv00; *(uint4*)&sRH[sl + 256] = rv01;
    *(uint4*)&sRL[sl] = rv10; *(uint4*)&sRL[sl + 256] = rv11;
    __syncthreads();   // B: tiles visible

    // ---- QK^T (split-3) ----
    f32x4 s4[4];
#pragma unroll
    for (int jf = 0; jf < 4; ++jf) {
      const int bs = rslot(jf, lane);
      short8 bh0 = sKH[bs], bh1 = sKH[256 + bs];
      short8 bl0 = sKL[bs], bl1 = sKL[256 + bs];
      f32x4 a = {0.f, 0.f, 0.f, 0.f};
      a = __builtin_amdgcn_mfma_f32_16x16x32_bf16(qf_h0, bh0, a, 0, 0, 0);
      a = __builtin_amdgcn_mfma_f32_16x16x32_bf16(qf_h1, bh1, a, 0, 0, 0);
      a = __builtin_amdgcn_mfma_f32_16x16x32_bf16(qf_h0, bl0, a, 0, 0, 0);
      a = __builtin_amdgcn_mfma_f32_16x16x32_bf16(qf_h1, bl1, a, 0, 0, 0);
      a = __builtin_amdgcn_mfma_f32_16x16x32_bf16(qf_l0, bh0, a, 0, 0, 0);
      a = __builtin_amdgcn_mfma_f32_16x16x32_bf16(qf_l1, bh1, a, 0, 0, 0);
      s4[jf] = a;
    }

    // ---- online softmax ----
#pragma unroll
    for (int e = 0; e < 4; ++e) {
      float v0 = fmaf(s4[0][e], 0.125f, pf[0][e]);
      float v1 = fmaf(s4[1][e], 0.125f, pf[1][e]);
      float v2 = fmaf(s4[2][e], 0.125f, pf[2][e]);
      float v3 = fmaf(s4[3][e], 0.125f, pf[3][e]);
      float tm = fmaxf(fmaxf(v0, v1), fmaxf(v2, v3));
#pragma unroll
      for (int off = 1; off < 16; off <<= 1) tm = fmaxf(tm, __shfl_xor(tm, off, 64));
      const float mn = fmaxf(m[e], tm);
      const float sc = __expf(m[e] - mn);
      v0 = __expf(v0 - mn); v1 = __expf(v1 - mn);
      v2 = __expf(v2 - mn); v3 = __expf(v3 - mn);
      float ts = (v0 + v1) + (v2 + v3);
#pragma unroll
      for (int off = 1; off < 16; off <<= 1) ts += __shfl_xor(ts, off, 64);
      l[e] = l[e] * sc + ts;
      m[e] = mn;
#pragma unroll
      for (int nf = 0; nf < 4; ++nf) o[nf][e] *= sc;
      PT[w][qr + e][ 0 + qc] = v0;
      PT[w][qr + e][16 + qc] = v1;
      PT[w][qr + e][32 + qc] = v2;
      PT[w][qr + e][48 + qc] = v3;
    }

    // ---- P frags + split ----
    short8 ph[2], pl[2];
#pragma unroll
    for (int h = 0; h < 2; ++h) {
      const float* psrc = &PT[w][lane & 15][h * 32 + (lane >> 4) * 8];
      float4 x = *(const float4*)&psrc[0];
      float4 y = *(const float4*)&psrc[4];
      float vv[8] = {x.x, x.y, x.z, x.w, y.x, y.y, y.z, y.w};
      ushort hh[8], ll[8];
#pragma unroll
      for (int u = 0; u < 8; ++u) split2t(vv[u], hh[u], ll[u]);
      ph[h] = *(short8*)&hh[0];
      pl[h] = *(short8*)&ll[0];
    }

    // ---- PV (split-3) ----
#pragma unroll
    for (int nf = 0; nf < 4; ++nf) {
      const int bs = rslot(nf, lane);
      short8 rh0 = sRH[bs], rh1 = sRH[256 + bs];
      short8 rl0 = sRL[bs], rl1 = sRL[256 + bs];
      f32x4 a = o[nf];
      a = __builtin_amdgcn_mfma_f32_16x16x32_bf16(ph[0], rh0, a, 0, 0, 0);
      a = __builtin_amdgcn_mfma_f32_16x16x32_bf16(ph[1], rh1, a, 0, 0, 0);
      a = __builtin_amdgcn_mfma_f32_16x16x32_bf16(ph[0], rl0, a, 0, 0, 0);
      a = __builtin_amdgcn_mfma_f32_16x16x32_bf16(ph[1], rl1, a, 0, 0, 0);
      a = __builtin_amdgcn_mfma_f32_16x16x32_bf16(pl[0], rh0, a, 0, 0, 0);
      a = __builtin_amdgcn_mfma_f32_16x16x32_bf16(pl[1], rh1, a, 0, 0, 0);
      o[nf] = a;
    }
  }

  const size_t idx = ((size_t)blockIdx.x * GG + g) * SPLIT + sp;
  float* pot = po + idx * 4096;
#pragma unroll
  for (int nf = 0; nf < 4; ++nf)
#pragma unroll
    for (int e = 0; e < 4; ++e)
      pot[(w * 16 + qr + e) * 64 + nf * 16 + qc] = o[nf][e];
  if (qc == 0) {
#pragma unroll
    for (int e = 0; e < 4; ++e) {
      const int row = w * 16 + qr + e;
      pstat[(idx * 64 + row) * 2]     = m[e];
      pstat[(idx * 64 + row) * 2 + 1] = l[e];
    }
  }
}

// ---------------------------------------------------------------------------
// Kernel 4b: combine split partials (+ residual + bias) -> per-block column
// partial sums (no res materialization — nothing reads it).
// ---------------------------------------------------------------------------
__global__ __launch_bounds__(256) void combine_k(
    const float* __restrict__ po, const float* __restrict__ pstat,
    const float* __restrict__ roi, const float* __restrict__ bconv,
    float* __restrict__ part2)
{
  __shared__ float T[64][68];
  const int it = blockIdx.x, g = blockIdx.y;
  const int t = threadIdx.x;
  const int row = t >> 2, c0 = (t & 3) * 16;
  const size_t base = ((size_t)it * GG + g) * SPLIT;

  float ms[SPLIT], ls[SPLIT];
#pragma unroll
  for (int s = 0; s < SPLIT; ++s) {
    float2 st = *(const float2*)&pstat[((base + s) * 64 + row) * 2];
    ms[s] = st.x; ls[s] = st.y;
  }
  float M = ms[0];
#pragma unroll
  for (int s = 1; s < SPLIT; ++s) M = fmaxf(M, ms[s]);
  float wgt[SPLIT], L = 0.f;
#pragma unroll
  for (int s = 0; s < SPLIT; ++s) { wgt[s] = __expf(ms[s] - M); L = fmaf(ls[s], wgt[s], L); }
  const float rL = 1.0f / L;

  const int grow = it * 64 + row;
  const int f0   = g * DGD + c0;
#pragma unroll
  for (int c = 0; c < 4; ++c) {
    float4 acc = {0.f, 0.f, 0.f, 0.f};
#pragma unroll
    for (int s = 0; s < SPLIT; ++s) {
      float4 v = *(const float4*)&po[(base + s) * 4096 + row * 64 + c0 + c * 4];
      acc.x = fmaf(v.x, wgt[s], acc.x);
      acc.y = fmaf(v.y, wgt[s], acc.y);
      acc.z = fmaf(v.z, wgt[s], acc.z);
      acc.w = fmaf(v.w, wgt[s], acc.w);
    }
    float4 r4 = *(const float4*)&roi[grow * NN + f0 + c * 4];
    float4 b4 = *(const float4*)&bconv[f0 + c * 4];
    float4 ov;
    ov.x = r4.x + b4.x + acc.x * rL;
    ov.y = r4.y + b4.y + acc.y * rL;
    ov.z = r4.z + b4.z + acc.z * rL;
    ov.w = r4.w + b4.w + acc.w * rL;
    *(float4*)&T[row][c0 + c * 4] = ov;
  }
  __syncthreads();
  if (t < 64) {
    float s = 0.f;
#pragma unroll 8
    for (int rr = 0; rr < 64; ++rr) s += T[rr][t];
    part2[(size_t)it * NN + g * DGD + t] = s;
  }
}

// ---------------------------------------------------------------------------
// Kernel 5: reduce 16 partials, logits = colsum@W_ro + b_ro, sigmoid.
// ---------------------------------------------------------------------------
__global__ __launch_bounds__(640) void final_k(
    const float* __restrict__ part2, const float* __restrict__ W_ro,
    const float* __restrict__ b_ro, float* __restrict__ out)
{
  __shared__ float cs[1024];
  __shared__ float red[8][CLS];
  const int t = threadIdx.x;

  for (int u = t; u < 1024; u += 640) {
    float s = 0.f;
#pragma unroll
    for (int p = 0; p < 16; ++p) s += part2[(size_t)p * NN + u];
    cs[u] = s;
  }
  __syncthreads();

  {
    const int c = t % CLS, s = t / CLS;
    float acc = 0.f;
    const int d0 = s * 128;
#pragma unroll 8
    for (int d = d0; d < d0 + 128; ++d)
      acc = fmaf(cs[d], W_ro[d * CLS + c], acc);
    red[s][c] = acc;
  }
  __syncthreads();

  if (t < CLS) {
    float lg = b_ro[t];
#pragma unroll
    for (int s = 0; s < 8; ++s) lg += red[s][t];
    out[t] = 1.0f / (1.0f + __expf(-lg));
  }
}

// ---------------------------------------------------------------------------
extern "C" void kernel_launch(void* const* d_in, const int* in_sizes, int n_in,
                              void* d_out, int out_size, void* d_ws, size_t ws_size,
                              hipStream_t stream) {
  const float* bbox  = (const float*)d_in[0];
  const float* roi   = (const float*)d_in[1];
  const float* W_pos = (const float*)d_in[2];
  const float* b_pos = (const float*)d_in[3];
  const float* Wq    = (const float*)d_in[4];
  const float* bq    = (const float*)d_in[5];
  const float* Wk    = (const float*)d_in[6];
  const float* bk    = (const float*)d_in[7];
  const float* Wc    = (const float*)d_in[8];
  const float* bcv   = (const float*)d_in[9];
  const float* W_ro  = (const float*)d_in[10];
  const float* b_ro  = (const float*)d_in[11];

  float* ws = (float*)d_ws;
  // A [0,8M) floats: paff as f16 (16M ushorts = 32 MB)
  ushort* paffh = (ushort*)ws;
  // A2 [8M,12M): po (SPLIT=4 -> 4M floats = 16 MB)
  float* po = ws + (8 << 20);
  // B [16M,20M): prep planes (prep_k -> fused_m); dead after fused_m
  ushort* roiH = (ushort*)(ws + (16 << 20));
  ushort* roiL = (ushort*)(ws + (16 << 20) + (1 << 19));
  ushort* WqTH = (ushort*)(ws + (17 << 20));
  ushort* WqTL = (ushort*)(ws + (17 << 20) + (1 << 19));
  ushort* WkTH = (ushort*)(ws + (18 << 20));
  ushort* WkTL = (ushort*)(ws + (18 << 20) + (1 << 19));
  ushort* WcH  = (ushort*)(ws + (19 << 20));
  ushort* WcL  = (ushort*)(ws + (19 << 20) + (1 << 19));
  // D [20M,23M): q/k/rw split planes (fused_m -> attn)
  ushort* qHp  = (ushort*)(ws + (20 << 20));
  ushort* qLp  = (ushort*)(ws + (20 << 20) + (1 << 19));
  ushort* kHp  = (ushort*)(ws + (21 << 20));
  ushort* kLp  = (ushort*)(ws + (21 << 20) + (1 << 19));
  ushort* rwHp = (ushort*)(ws + (22 << 20));
  ushort* rwLp = (ushort*)(ws + (22 << 20) + (1 << 19));
  // E [23M,24M): pstat (128K floats), part2 (16K). Total 96 MB.
  float* pstat = ws + (23 << 20);                    // 128K floats
  float* part2 = ws + (23 << 20) + (1 << 18);        // 16K floats

  prep_k<<<1024, 256, 0, stream>>>(roi, roiH, roiL, Wc, WcH, WcL,
                                   Wq, Wk, WqTH, WqTL, WkTH, WkTL);

  fused_m<<<1792, 256, 0, stream>>>(bbox, W_pos, b_pos,
                                    roiH, roiL, WqTH, WqTL, WkTH, WkTL,
                                    WcH, WcL, bq, bk,
                                    qHp, qLp, kHp, kLp, rwHp, rwLp, paffh);

  attn_m<<<dim3(16, 16, SPLIT), 256, 0, stream>>>(qHp, qLp, kHp, kLp, rwHp, rwLp,
                                                  paffh, po, pstat);
  combine_k<<<dim3(16, 16), 256, 0, stream>>>(po, pstat, roi, bcv, part2);
  final_k<<<1, 640, 0, stream>>>(part2, W_ro, b_ro, (float*)d_out);
}